// Round 1
// baseline (734.912 us; speedup 1.0000x reference)
//
#include <hip/hip_runtime.h>

// ---------------------------------------------------------------------------
// GAT 2-layer encoder. N=100k nodes, E=1.6M edges, 128->128(relu)->64.
// Strategy:
//   a_dst = x . (W_dst @ att_dst)  (h_dst never materialized)
//   CSR-by-dst built per launch (histogram + scan + scatter)
//   one wave per dst node: softmax-max, softmax-denom, weighted aggregate
// ---------------------------------------------------------------------------

__global__ void matvec_kernel(const float* __restrict__ W, const float* __restrict__ a,
                              float* __restrict__ out, int rows, int cols) {
    int i = blockIdx.x * blockDim.x + threadIdx.x;
    if (i >= rows) return;
    float s = 0.f;
    for (int j = 0; j < cols; ++j) s += W[i * cols + j] * a[j];
    out[i] = s;
}

__global__ void hist_kernel(const int* __restrict__ dst, int* __restrict__ cnt, int E) {
    int i = blockIdx.x * blockDim.x + threadIdx.x;
    if (i < E) atomicAdd(&cnt[dst[i]], 1);
}

__global__ void scan_block_kernel(const int* __restrict__ cnt, int* __restrict__ offs,
                                  int* __restrict__ bsums, int n) {
    __shared__ int s[256];
    int tid = threadIdx.x;
    int i = blockIdx.x * 256 + tid;
    int v = (i < n) ? cnt[i] : 0;
    s[tid] = v;
    __syncthreads();
    for (int o = 1; o < 256; o <<= 1) {
        int t = (tid >= o) ? s[tid - o] : 0;
        __syncthreads();
        s[tid] += t;
        __syncthreads();
    }
    if (i < n) offs[i] = s[tid] - v;           // exclusive
    if (tid == 255) bsums[blockIdx.x] = s[255];
}

__global__ void scan_top_kernel(int* __restrict__ bsums, int nb) {
    __shared__ int s[512];
    int tid = threadIdx.x;
    int v = (tid < nb) ? bsums[tid] : 0;
    s[tid] = v;
    __syncthreads();
    for (int o = 1; o < 512; o <<= 1) {
        int t = (tid >= o) ? s[tid - o] : 0;
        __syncthreads();
        s[tid] += t;
        __syncthreads();
    }
    if (tid < nb) bsums[tid] = s[tid] - v;     // exclusive
}

__global__ void scan_fin_kernel(int* __restrict__ offs, const int* __restrict__ bsums,
                                int* __restrict__ cur, int n, int total) {
    int i = blockIdx.x * 256 + threadIdx.x;
    if (i < n) {
        int v = offs[i] + bsums[blockIdx.x];
        offs[i] = v;
        cur[i] = v;
    }
    if (i == 0) offs[n] = total;
}

__global__ void scatter_kernel(const int* __restrict__ src, const int* __restrict__ dst,
                               int* __restrict__ cur, int* __restrict__ srcs, int E) {
    int i = blockIdx.x * blockDim.x + threadIdx.x;
    if (i < E) {
        int p = atomicAdd(&cur[dst[i]], 1);
        srcs[p] = src[i];
    }
}

// H = X @ W  (X:[M,128], W:[128,C]); fused epilogue:
//   aS[m] = H[m,:] . attS     aD[m] = X[m,:] . wda
template <int C>
__global__ __launch_bounds__(512) void gemm_att_kernel(
    const float* __restrict__ X, const float* __restrict__ W,
    const float* __restrict__ attS, const float* __restrict__ wda,
    float* __restrict__ H, float* __restrict__ aS, float* __restrict__ aD, int M) {
    constexpr int ROWS = 64;
    constexpr int TC = C / 8;  // cols per thread (16 or 8)
    __shared__ float Xs[ROWS][68];       // 64 k-cols + pad
    __shared__ float Ws[64 * C];         // half of W along K

    const int t = threadIdx.x;
    const int m0 = blockIdx.x * ROWS;
    const int row = t >> 3;
    const int cg = t & 7;
    const int cb = cg * TC;

    float acc[TC];
#pragma unroll
    for (int i = 0; i < TC; ++i) acc[i] = 0.f;
    float pd = 0.f;

    for (int kk = 0; kk < 128; kk += 64) {
        // load W half: rows kk..kk+63
        {
            const float4* Wg = (const float4*)(W + kk * C);
            float4* WsV = (float4*)Ws;
#pragma unroll
            for (int i = 0; i < C / 32; ++i) WsV[i * 512 + t] = Wg[i * 512 + t];
        }
        // load X half: 64 rows x 64 cols
        {
#pragma unroll
            for (int i = 0; i < 2; ++i) {
                int f4 = i * 512 + t;      // 0..1023
                int r = f4 >> 4;           // 16 float4 per row
                int c = (f4 & 15) * 4;
                int gr = m0 + r;
                float4 v = make_float4(0.f, 0.f, 0.f, 0.f);
                if (gr < M) v = *(const float4*)(X + (size_t)gr * 128 + kk + c);
                Xs[r][c] = v.x; Xs[r][c + 1] = v.y; Xs[r][c + 2] = v.z; Xs[r][c + 3] = v.w;
            }
        }
        __syncthreads();
#pragma unroll 4
        for (int k = 0; k < 64; ++k) {
            float xv = Xs[row][k];
            const float* wr = &Ws[k * C + cb];
#pragma unroll
            for (int i = 0; i < TC; ++i) acc[i] += xv * wr[i];
        }
        // a_dst partial: this thread's 8-k segment of the half
        {
            int kb = cg * 8;
#pragma unroll
            for (int j = 0; j < 8; ++j) pd += Xs[row][kb + j] * wda[kk + kb + j];
        }
        __syncthreads();
    }

    int gr = m0 + row;
    if (gr < M) {
#pragma unroll
        for (int i = 0; i < TC; i += 4)
            *(float4*)(H + (size_t)gr * C + cb + i) =
                make_float4(acc[i], acc[i + 1], acc[i + 2], acc[i + 3]);
        float ps = 0.f;
#pragma unroll
        for (int i = 0; i < TC; ++i) ps += acc[i] * attS[cb + i];
#pragma unroll
        for (int o = 4; o; o >>= 1) {
            ps += __shfl_down(ps, o, 8);
            pd += __shfl_down(pd, o, 8);
        }
        if (cg == 0) { aS[gr] = ps; aD[gr] = pd; }
    }
}

// One wave per destination node: segment softmax + weighted aggregation.
template <int C, bool RELU>
__global__ __launch_bounds__(256) void aggregate_kernel(
    const int* __restrict__ offs, const int* __restrict__ srcs,
    const float* __restrict__ hsrc, const float* __restrict__ aS,
    const float* __restrict__ aD, const float* __restrict__ bias,
    float* __restrict__ out, int n) {
    int node = (int)((blockIdx.x * blockDim.x + threadIdx.x) >> 6);
    int lane = threadIdx.x & 63;
    if (node >= n) return;
    int beg = offs[node], end = offs[node + 1];
    float ad = aD[node];

    // pass 1: max logit
    float m = -INFINITY;
    for (int i = beg + lane; i < end; i += 64) {
        float l = aS[srcs[i]] + ad;
        l = (l > 0.f) ? l : 0.2f * l;
        m = fmaxf(m, l);
    }
#pragma unroll
    for (int o = 32; o; o >>= 1) m = fmaxf(m, __shfl_xor(m, o, 64));

    // pass 2: denom
    float s = 0.f;
    for (int i = beg + lane; i < end; i += 64) {
        float l = aS[srcs[i]] + ad;
        l = (l > 0.f) ? l : 0.2f * l;
        s += __expf(l - m);
    }
#pragma unroll
    for (int o = 32; o; o >>= 1) s += __shfl_xor(s, o, 64);
    float inv = 1.f / (s + 1e-16f);

    if constexpr (C == 128) {
        float ax = 0.f, ay = 0.f;
        for (int base = beg; base < end; base += 64) {
            int i = base + lane;
            float w = 0.f;
            int sj = 0;
            if (i < end) {
                sj = srcs[i];
                float l = aS[sj] + ad;
                l = (l > 0.f) ? l : 0.2f * l;
                w = __expf(l - m) * inv;
            }
            int cnt = min(64, end - base);
            for (int j = 0; j < cnt; ++j) {
                float wj = __shfl(w, j, 64);
                int sr = __shfl(sj, j, 64);
                float2 v = *(const float2*)(hsrc + (size_t)sr * 128 + lane * 2);
                ax += wj * v.x;
                ay += wj * v.y;
            }
        }
        float ox = ax + bias[lane * 2];
        float oy = ay + bias[lane * 2 + 1];
        if (RELU) { ox = fmaxf(ox, 0.f); oy = fmaxf(oy, 0.f); }
        *(float2*)(out + (size_t)node * 128 + lane * 2) = make_float2(ox, oy);
    } else {
        float a0 = 0.f;
        for (int base = beg; base < end; base += 64) {
            int i = base + lane;
            float w = 0.f;
            int sj = 0;
            if (i < end) {
                sj = srcs[i];
                float l = aS[sj] + ad;
                l = (l > 0.f) ? l : 0.2f * l;
                w = __expf(l - m) * inv;
            }
            int cnt = min(64, end - base);
            for (int j = 0; j < cnt; ++j) {
                float wj = __shfl(w, j, 64);
                int sr = __shfl(sj, j, 64);
                a0 += wj * hsrc[(size_t)sr * 64 + lane];
            }
        }
        float o0 = a0 + bias[lane];
        if (RELU) o0 = fmaxf(o0, 0.f);
        out[(size_t)node * 64 + lane] = o0;
    }
}

extern "C" void kernel_launch(void* const* d_in, const int* in_sizes, int n_in,
                              void* d_out, int out_size, void* d_ws, size_t ws_size,
                              hipStream_t stream) {
    const float* x     = (const float*)d_in[0];
    const int*   edge  = (const int*)d_in[1];
    const float* W1s   = (const float*)d_in[2];
    const float* W1d   = (const float*)d_in[3];
    const float* att1s = (const float*)d_in[4];
    const float* att1d = (const float*)d_in[5];
    const float* b1    = (const float*)d_in[6];
    const float* W2s   = (const float*)d_in[7];
    const float* W2d   = (const float*)d_in[8];
    const float* att2s = (const float*)d_in[9];
    const float* att2d = (const float*)d_in[10];
    const float* b2    = (const float*)d_in[11];

    const int N = in_sizes[0] / 128;
    const int E = in_sizes[1] / 2;
    const int* srcI = edge;
    const int* dstI = edge + E;

    // workspace carve (256-B aligned)
    size_t off = 0;
    auto alloc = [&](size_t bytes) {
        void* p = (char*)d_ws + off;
        off += (bytes + 255) & ~(size_t)255;
        return p;
    };
    int*   offs  = (int*)alloc((size_t)(N + 1) * 4);
    int*   cur   = (int*)alloc((size_t)N * 4);
    int*   srcs  = (int*)alloc((size_t)E * 4);
    int*   bsums = (int*)alloc(512 * 4);
    float* watt1 = (float*)alloc(128 * 4);
    float* watt2 = (float*)alloc(128 * 4);
    float* a_s   = (float*)alloc((size_t)N * 4);
    float* a_d   = (float*)alloc((size_t)N * 4);
    float* h_s   = (float*)alloc((size_t)N * 128 * 4);  // h1_src then h2_src
    float* h1    = (float*)alloc((size_t)N * 128 * 4);  // relu(layer1 out)

    hipMemsetAsync(cur, 0, (size_t)N * 4, stream);
    matvec_kernel<<<1, 128, 0, stream>>>(W1d, att1d, watt1, 128, 128);
    matvec_kernel<<<1, 128, 0, stream>>>(W2d, att2d, watt2, 128, 64);

    int nb = (N + 255) / 256;
    hist_kernel<<<(E + 255) / 256, 256, 0, stream>>>(dstI, cur, E);
    scan_block_kernel<<<nb, 256, 0, stream>>>(cur, offs, bsums, N);
    scan_top_kernel<<<1, 512, 0, stream>>>(bsums, nb);
    scan_fin_kernel<<<nb, 256, 0, stream>>>(offs, bsums, cur, N, E);
    scatter_kernel<<<(E + 255) / 256, 256, 0, stream>>>(srcI, dstI, cur, srcs, E);

    int gblk = (N + 63) / 64;
    gemm_att_kernel<128><<<gblk, 512, 0, stream>>>(x, W1s, att1s, watt1, h_s, a_s, a_d, N);
    aggregate_kernel<128, true><<<(N + 3) / 4, 256, 0, stream>>>(offs, srcs, h_s, a_s, a_d, b1, h1, N);
    gemm_att_kernel<64><<<gblk, 512, 0, stream>>>(h1, W2s, att2s, watt2, h_s, a_s, a_d, N);
    aggregate_kernel<64, false><<<(N + 3) / 4, 256, 0, stream>>>(offs, srcs, h_s, a_s, a_d, b2, (float*)d_out, N);
}

// Round 2
// 647.054 us; speedup vs baseline: 1.1358x; 1.1358x over previous
//
#include <hip/hip_runtime.h>

// ---------------------------------------------------------------------------
// GAT 2-layer encoder. N=100k nodes, E=1.6M edges, 128->128(relu)->64.
//   a_dst = x . (W_dst @ att_dst)  (h_dst never materialized)
//   CSR-by-dst built per launch (histogram + scan + scatter)
//   one wave per dst node: fused segment softmax + grouped gather-aggregate
// ---------------------------------------------------------------------------

__global__ void matvec_kernel(const float* __restrict__ W, const float* __restrict__ a,
                              float* __restrict__ out, int rows, int cols) {
    int i = blockIdx.x * blockDim.x + threadIdx.x;
    if (i >= rows) return;
    float s = 0.f;
    for (int j = 0; j < cols; ++j) s += W[i * cols + j] * a[j];
    out[i] = s;
}

__global__ void hist_kernel(const int* __restrict__ dst, int* __restrict__ cnt, int E) {
    int i = blockIdx.x * blockDim.x + threadIdx.x;
    if (i < E) atomicAdd(&cnt[dst[i]], 1);
}

__global__ void scan_block_kernel(const int* __restrict__ cnt, int* __restrict__ offs,
                                  int* __restrict__ bsums, int n) {
    __shared__ int s[256];
    int tid = threadIdx.x;
    int i = blockIdx.x * 256 + tid;
    int v = (i < n) ? cnt[i] : 0;
    s[tid] = v;
    __syncthreads();
    for (int o = 1; o < 256; o <<= 1) {
        int t = (tid >= o) ? s[tid - o] : 0;
        __syncthreads();
        s[tid] += t;
        __syncthreads();
    }
    if (i < n) offs[i] = s[tid] - v;           // exclusive
    if (tid == 255) bsums[blockIdx.x] = s[255];
}

__global__ void scan_top_kernel(int* __restrict__ bsums, int nb) {
    __shared__ int s[512];
    int tid = threadIdx.x;
    int v = (tid < nb) ? bsums[tid] : 0;
    s[tid] = v;
    __syncthreads();
    for (int o = 1; o < 512; o <<= 1) {
        int t = (tid >= o) ? s[tid - o] : 0;
        __syncthreads();
        s[tid] += t;
        __syncthreads();
    }
    if (tid < nb) bsums[tid] = s[tid] - v;     // exclusive
}

__global__ void scan_fin_kernel(int* __restrict__ offs, const int* __restrict__ bsums,
                                int* __restrict__ cur, int n, int total) {
    int i = blockIdx.x * 256 + threadIdx.x;
    if (i < n) {
        int v = offs[i] + bsums[blockIdx.x];
        offs[i] = v;
        cur[i] = v;
    }
    if (i == 0) offs[n] = total;
}

__global__ void scatter_kernel(const int* __restrict__ src, const int* __restrict__ dst,
                               int* __restrict__ cur, int* __restrict__ srcs, int E) {
    int i = blockIdx.x * blockDim.x + threadIdx.x;
    if (i < E) {
        int p = atomicAdd(&cur[dst[i]], 1);
        srcs[p] = src[i];
    }
}

// H = X @ W  (X:[M,128], W:[128,C]); fused epilogue:
//   aS[m] = H[m,:] . attS     aD[m] = X[m,:] . wda
template <int C>
__global__ __launch_bounds__(512) void gemm_att_kernel(
    const float* __restrict__ X, const float* __restrict__ W,
    const float* __restrict__ attS, const float* __restrict__ wda,
    float* __restrict__ H, float* __restrict__ aS, float* __restrict__ aD, int M) {
    constexpr int ROWS = 64;
    constexpr int TC = C / 8;  // cols per thread (16 or 8)
    __shared__ float Xs[ROWS][68];       // 64 k-cols + pad
    __shared__ float Ws[64 * C];         // half of W along K

    const int t = threadIdx.x;
    const int m0 = blockIdx.x * ROWS;
    const int row = t >> 3;
    const int cg = t & 7;
    const int cb = cg * TC;

    float acc[TC];
#pragma unroll
    for (int i = 0; i < TC; ++i) acc[i] = 0.f;
    float pd = 0.f;

    for (int kk = 0; kk < 128; kk += 64) {
        // load W half: rows kk..kk+63
        {
            const float4* Wg = (const float4*)(W + kk * C);
            float4* WsV = (float4*)Ws;
#pragma unroll
            for (int i = 0; i < C / 32; ++i) WsV[i * 512 + t] = Wg[i * 512 + t];
        }
        // load X half: 64 rows x 64 cols
        {
#pragma unroll
            for (int i = 0; i < 2; ++i) {
                int f4 = i * 512 + t;      // 0..1023
                int r = f4 >> 4;           // 16 float4 per row
                int c = (f4 & 15) * 4;
                int gr = m0 + r;
                float4 v = make_float4(0.f, 0.f, 0.f, 0.f);
                if (gr < M) v = *(const float4*)(X + (size_t)gr * 128 + kk + c);
                Xs[r][c] = v.x; Xs[r][c + 1] = v.y; Xs[r][c + 2] = v.z; Xs[r][c + 3] = v.w;
            }
        }
        __syncthreads();
#pragma unroll 4
        for (int k = 0; k < 64; ++k) {
            float xv = Xs[row][k];
            const float* wr = &Ws[k * C + cb];
#pragma unroll
            for (int i = 0; i < TC; ++i) acc[i] += xv * wr[i];
        }
        // a_dst partial: this thread's 8-k segment of the half
        {
            int kb = cg * 8;
#pragma unroll
            for (int j = 0; j < 8; ++j) pd += Xs[row][kb + j] * wda[kk + kb + j];
        }
        __syncthreads();
    }

    int gr = m0 + row;
    if (gr < M) {
#pragma unroll
        for (int i = 0; i < TC; i += 4)
            *(float4*)(H + (size_t)gr * C + cb + i) =
                make_float4(acc[i], acc[i + 1], acc[i + 2], acc[i + 3]);
        float ps = 0.f;
#pragma unroll
        for (int i = 0; i < TC; ++i) ps += acc[i] * attS[cb + i];
#pragma unroll
        for (int o = 4; o; o >>= 1) {
            ps += __shfl_down(ps, o, 8);
            pd += __shfl_down(pd, o, 8);
        }
        if (cg == 0) { aS[gr] = ps; aD[gr] = pd; }
    }
}

// Grouped accumulate of one <=64-edge chunk: 4 groups of 16 lanes, each group
// handles one edge per step with dwordx4 loads. Padded edges carry w=0.
template <int C>
__device__ __forceinline__ void agg_chunk(float w, int sj, int cnt, int lane,
                                          const float* __restrict__ hsrc, float* acc) {
    const int g = lane >> 4;
    const int l = lane & 15;
    const int jm = (cnt + 3) >> 2;
#pragma unroll 4
    for (int j = 0; j < jm; ++j) {
        int e = j * 4 + g;
        float wj = __shfl(w, e, 64);
        int sr = __shfl(sj, e, 64);
        if constexpr (C == 128) {
            const float4* p = (const float4*)(hsrc + ((size_t)sr << 7)) + l * 2;
            float4 v0 = p[0];
            float4 v1 = p[1];
            acc[0] += wj * v0.x; acc[1] += wj * v0.y; acc[2] += wj * v0.z; acc[3] += wj * v0.w;
            acc[4] += wj * v1.x; acc[5] += wj * v1.y; acc[6] += wj * v1.z; acc[7] += wj * v1.w;
        } else {
            const float4* p = (const float4*)(hsrc + ((size_t)sr << 6)) + l;
            float4 v = p[0];
            acc[0] += wj * v.x; acc[1] += wj * v.y; acc[2] += wj * v.z; acc[3] += wj * v.w;
        }
    }
}

// One wave per destination node: segment softmax + weighted aggregation.
template <int C, bool RELU>
__global__ __launch_bounds__(256) void aggregate_kernel(
    const int* __restrict__ offs, const int* __restrict__ srcs,
    const float* __restrict__ hsrc, const float* __restrict__ aS,
    const float* __restrict__ aD, const float* __restrict__ bias,
    float* __restrict__ out, int n) {
    int node = (int)((blockIdx.x * blockDim.x + threadIdx.x) >> 6);
    int lane = threadIdx.x & 63;
    if (node >= n) return;
    int beg = offs[node], end = offs[node + 1];
    int deg = end - beg;
    float ad = aD[node];

    constexpr int NA = (C == 128) ? 8 : 4;
    float acc[NA];
#pragma unroll
    for (int i = 0; i < NA; ++i) acc[i] = 0.f;

    if (deg <= 64) {
        // ---- fused fast path: one gather + one exp per edge ----
        int i = beg + lane;
        int sj = 0;
        float lv = -INFINITY;
        if (i < end) {
            sj = srcs[i];
            float l = aS[sj] + ad;
            lv = (l > 0.f) ? l : 0.2f * l;
        }
        float m = lv;
#pragma unroll
        for (int o = 32; o; o >>= 1) m = fmaxf(m, __shfl_xor(m, o, 64));
        float e = (i < end) ? __expf(lv - m) : 0.f;
        float s = e;
#pragma unroll
        for (int o = 32; o; o >>= 1) s += __shfl_xor(s, o, 64);
        float w = e * (1.f / (s + 1e-16f));
        agg_chunk<C>(w, sj, deg, lane, hsrc, acc);
    } else {
        // ---- generic chunked path (deg > 64, rare) ----
        float m = -INFINITY;
        for (int i = beg + lane; i < end; i += 64) {
            float l = aS[srcs[i]] + ad;
            l = (l > 0.f) ? l : 0.2f * l;
            m = fmaxf(m, l);
        }
#pragma unroll
        for (int o = 32; o; o >>= 1) m = fmaxf(m, __shfl_xor(m, o, 64));
        float s = 0.f;
        for (int i = beg + lane; i < end; i += 64) {
            float l = aS[srcs[i]] + ad;
            l = (l > 0.f) ? l : 0.2f * l;
            s += __expf(l - m);
        }
#pragma unroll
        for (int o = 32; o; o >>= 1) s += __shfl_xor(s, o, 64);
        float inv = 1.f / (s + 1e-16f);
        for (int base = beg; base < end; base += 64) {
            int i = base + lane;
            int sj = 0;
            float w = 0.f;
            if (i < end) {
                sj = srcs[i];
                float l = aS[sj] + ad;
                l = (l > 0.f) ? l : 0.2f * l;
                w = __expf(l - m) * inv;
            }
            agg_chunk<C>(w, sj, min(64, end - base), lane, hsrc, acc);
        }
    }

    // cross-group reduce: groups 0..3 hold partial sums for the same cols
#pragma unroll
    for (int i = 0; i < NA; ++i) {
        acc[i] += __shfl_xor(acc[i], 16, 64);
        acc[i] += __shfl_xor(acc[i], 32, 64);
    }

    if (lane < 16) {
        if constexpr (C == 128) {
            int c0 = lane * 8;
            const float4* b4 = (const float4*)(bias + c0);
            float4 b0 = b4[0], b1 = b4[1];
            float4 o0 = make_float4(acc[0] + b0.x, acc[1] + b0.y, acc[2] + b0.z, acc[3] + b0.w);
            float4 o1 = make_float4(acc[4] + b1.x, acc[5] + b1.y, acc[6] + b1.z, acc[7] + b1.w);
            if (RELU) {
                o0.x = fmaxf(o0.x, 0.f); o0.y = fmaxf(o0.y, 0.f);
                o0.z = fmaxf(o0.z, 0.f); o0.w = fmaxf(o0.w, 0.f);
                o1.x = fmaxf(o1.x, 0.f); o1.y = fmaxf(o1.y, 0.f);
                o1.z = fmaxf(o1.z, 0.f); o1.w = fmaxf(o1.w, 0.f);
            }
            float4* op = (float4*)(out + (size_t)node * 128 + c0);
            op[0] = o0;
            op[1] = o1;
        } else {
            int c0 = lane * 4;
            float4 b0 = *(const float4*)(bias + c0);
            float4 o0 = make_float4(acc[0] + b0.x, acc[1] + b0.y, acc[2] + b0.z, acc[3] + b0.w);
            if (RELU) {
                o0.x = fmaxf(o0.x, 0.f); o0.y = fmaxf(o0.y, 0.f);
                o0.z = fmaxf(o0.z, 0.f); o0.w = fmaxf(o0.w, 0.f);
            }
            *(float4*)(out + (size_t)node * 64 + c0) = o0;
        }
    }
}

extern "C" void kernel_launch(void* const* d_in, const int* in_sizes, int n_in,
                              void* d_out, int out_size, void* d_ws, size_t ws_size,
                              hipStream_t stream) {
    const float* x     = (const float*)d_in[0];
    const int*   edge  = (const int*)d_in[1];
    const float* W1s   = (const float*)d_in[2];
    const float* W1d   = (const float*)d_in[3];
    const float* att1s = (const float*)d_in[4];
    const float* att1d = (const float*)d_in[5];
    const float* b1    = (const float*)d_in[6];
    const float* W2s   = (const float*)d_in[7];
    const float* W2d   = (const float*)d_in[8];
    const float* att2s = (const float*)d_in[9];
    const float* att2d = (const float*)d_in[10];
    const float* b2    = (const float*)d_in[11];

    const int N = in_sizes[0] / 128;
    const int E = in_sizes[1] / 2;
    const int* srcI = edge;
    const int* dstI = edge + E;

    // workspace carve (256-B aligned)
    size_t off = 0;
    auto alloc = [&](size_t bytes) {
        void* p = (char*)d_ws + off;
        off += (bytes + 255) & ~(size_t)255;
        return p;
    };
    int*   offs  = (int*)alloc((size_t)(N + 1) * 4);
    int*   cur   = (int*)alloc((size_t)N * 4);
    int*   srcs  = (int*)alloc((size_t)E * 4);
    int*   bsums = (int*)alloc(512 * 4);
    float* watt1 = (float*)alloc(128 * 4);
    float* watt2 = (float*)alloc(128 * 4);
    float* a_s   = (float*)alloc((size_t)N * 4);
    float* a_d   = (float*)alloc((size_t)N * 4);
    float* h_s   = (float*)alloc((size_t)N * 128 * 4);  // h1_src then h2_src
    float* h1    = (float*)alloc((size_t)N * 128 * 4);  // relu(layer1 out)

    hipMemsetAsync(cur, 0, (size_t)N * 4, stream);
    matvec_kernel<<<1, 128, 0, stream>>>(W1d, att1d, watt1, 128, 128);
    matvec_kernel<<<1, 128, 0, stream>>>(W2d, att2d, watt2, 128, 64);

    int nb = (N + 255) / 256;
    hist_kernel<<<(E + 255) / 256, 256, 0, stream>>>(dstI, cur, E);
    scan_block_kernel<<<nb, 256, 0, stream>>>(cur, offs, bsums, N);
    scan_top_kernel<<<1, 512, 0, stream>>>(bsums, nb);
    scan_fin_kernel<<<nb, 256, 0, stream>>>(offs, bsums, cur, N, E);
    scatter_kernel<<<(E + 255) / 256, 256, 0, stream>>>(srcI, dstI, cur, srcs, E);

    int gblk = (N + 63) / 64;
    gemm_att_kernel<128><<<gblk, 512, 0, stream>>>(x, W1s, att1s, watt1, h_s, a_s, a_d, N);
    aggregate_kernel<128, true><<<(N + 3) / 4, 256, 0, stream>>>(offs, srcs, h_s, a_s, a_d, b1, h1, N);
    gemm_att_kernel<64><<<gblk, 512, 0, stream>>>(h1, W2s, att2s, watt2, h_s, a_s, a_d, N);
    aggregate_kernel<64, false><<<(N + 3) / 4, 256, 0, stream>>>(offs, srcs, h_s, a_s, a_d, b2, (float*)d_out, N);
}

// Round 3
// 596.219 us; speedup vs baseline: 1.2326x; 1.0853x over previous
//
#include <hip/hip_runtime.h>

// ---------------------------------------------------------------------------
// GAT 2-layer encoder. N=100k nodes, E=1.6M edges, 128->128(relu)->64.
//   a_dst = x . (W_dst @ att_dst)  (h_dst never materialized)
//   CSR-by-dst built per launch (histogram + scan + scatter)
//   register-tiled fp32 GEMM (4x8 per thread, conflict-free LDS)
//   one wave per dst node: fused segment softmax + grouped gather-aggregate
// ---------------------------------------------------------------------------

__global__ void matvec_kernel(const float* __restrict__ W, const float* __restrict__ a,
                              float* __restrict__ out, int rows, int cols) {
    int i = blockIdx.x * blockDim.x + threadIdx.x;
    if (i >= rows) return;
    float s = 0.f;
    for (int j = 0; j < cols; ++j) s += W[i * cols + j] * a[j];
    out[i] = s;
}

__global__ void hist_kernel(const int* __restrict__ dst, int* __restrict__ cnt, int E) {
    int i = blockIdx.x * blockDim.x + threadIdx.x;
    if (i < E) atomicAdd(&cnt[dst[i]], 1);
}

__global__ void scan_block_kernel(const int* __restrict__ cnt, int* __restrict__ offs,
                                  int* __restrict__ bsums, int n) {
    __shared__ int s[256];
    int tid = threadIdx.x;
    int i = blockIdx.x * 256 + tid;
    int v = (i < n) ? cnt[i] : 0;
    s[tid] = v;
    __syncthreads();
    for (int o = 1; o < 256; o <<= 1) {
        int t = (tid >= o) ? s[tid - o] : 0;
        __syncthreads();
        s[tid] += t;
        __syncthreads();
    }
    if (i < n) offs[i] = s[tid] - v;           // exclusive
    if (tid == 255) bsums[blockIdx.x] = s[255];
}

__global__ void scan_top_kernel(int* __restrict__ bsums, int nb) {
    __shared__ int s[512];
    int tid = threadIdx.x;
    int v = (tid < nb) ? bsums[tid] : 0;
    s[tid] = v;
    __syncthreads();
    for (int o = 1; o < 512; o <<= 1) {
        int t = (tid >= o) ? s[tid - o] : 0;
        __syncthreads();
        s[tid] += t;
        __syncthreads();
    }
    if (tid < nb) bsums[tid] = s[tid] - v;     // exclusive
}

__global__ void scan_fin_kernel(int* __restrict__ offs, const int* __restrict__ bsums,
                                int* __restrict__ cur, int n, int total) {
    int i = blockIdx.x * 256 + threadIdx.x;
    if (i < n) {
        int v = offs[i] + bsums[blockIdx.x];
        offs[i] = v;
        cur[i] = v;
    }
    if (i == 0) offs[n] = total;
}

__global__ void scatter_kernel(const int* __restrict__ src, const int* __restrict__ dst,
                               int* __restrict__ cur, int* __restrict__ srcs, int E) {
    int i = blockIdx.x * blockDim.x + threadIdx.x;
    if (i < E) {
        int p = atomicAdd(&cur[dst[i]], 1);
        srcs[p] = src[i];
    }
}

// H = X @ W  (X:[M,128], W:[128,C]); fused epilogue:
//   aS[m] = H[m,:] . attS     aD[m] = X[m,:] . wda
// 64 rows x C cols per block. Thread (rg,cg): rows rg*4..+3,
// cols {cg*4..+3} (and {64+cg*4..+3} for C=128). Register tile 4x(4*NB).
template <int C>
__global__ __launch_bounds__(256) void gemm_att_kernel(
    const float* __restrict__ X, const float* __restrict__ W,
    const float* __restrict__ attS, const float* __restrict__ wda,
    float* __restrict__ H, float* __restrict__ aS, float* __restrict__ aD, int M) {
    constexpr int NB = (C == 128) ? 2 : 1;
    __shared__ float4 Xs[16 * 65];          // [k4][row], k4-coeff 65 rotates banks
    __shared__ float  Ws[64 * C];           // k-major half of W

    const int t  = threadIdx.x;
    const int m0 = blockIdx.x * 64;
    const int rg = t >> 4;                  // 0..15 row group
    const int cg = t & 15;                  // 0..15 col group

    float4 acc[4][NB];
#pragma unroll
    for (int j = 0; j < 4; ++j)
#pragma unroll
        for (int b = 0; b < NB; ++b) acc[j][b] = make_float4(0.f, 0.f, 0.f, 0.f);
    float pd[4] = {0.f, 0.f, 0.f, 0.f};

    for (int kk = 0; kk < 128; kk += 64) {
        // stage W half (linear float4 copy, conflict-free)
        {
            const float4* Wg = (const float4*)(W + (size_t)kk * C);
            float4* WsV = (float4*)Ws;
#pragma unroll
            for (int i = 0; i < C / 16; ++i) WsV[i * 256 + t] = Wg[i * 256 + t];
        }
        // stage X half, k4-blocked: Xs[k4][row] = X[row][4*k4..+3]
#pragma unroll
        for (int i = 0; i < 4; ++i) {
            int f4 = i * 256 + t;
            int row = f4 >> 4;
            int k4 = f4 & 15;
            int gr = m0 + row;
            float4 v = make_float4(0.f, 0.f, 0.f, 0.f);
            if (gr < M) v = *(const float4*)(X + (size_t)gr * 128 + kk + k4 * 4);
            Xs[k4 * 65 + row] = v;
        }
        __syncthreads();

#pragma unroll 4
        for (int k4 = 0; k4 < 16; ++k4) {
            float4 a[4];
#pragma unroll
            for (int j = 0; j < 4; ++j) a[j] = Xs[k4 * 65 + rg * 4 + j];
            const float* wrow = Ws + k4 * 4 * C;
            const float* wd = wda + kk + k4 * 4;
#pragma unroll
            for (int u = 0; u < 4; ++u) {
                float4 b0 = *(const float4*)(wrow + u * C + cg * 4);
                float wdu = wd[u];
                float av[4];
#pragma unroll
                for (int j = 0; j < 4; ++j) av[j] = ((const float*)&a[j])[u];
#pragma unroll
                for (int j = 0; j < 4; ++j) {
                    acc[j][0].x += av[j] * b0.x;
                    acc[j][0].y += av[j] * b0.y;
                    acc[j][0].z += av[j] * b0.z;
                    acc[j][0].w += av[j] * b0.w;
                    pd[j] += av[j] * wdu;
                }
                if constexpr (NB == 2) {
                    float4 b1 = *(const float4*)(wrow + u * C + 64 + cg * 4);
#pragma unroll
                    for (int j = 0; j < 4; ++j) {
                        acc[j][1].x += av[j] * b1.x;
                        acc[j][1].y += av[j] * b1.y;
                        acc[j][1].z += av[j] * b1.z;
                        acc[j][1].w += av[j] * b1.w;
                    }
                }
            }
        }
        __syncthreads();
    }

    // epilogue: H store + aS/aD
    float4 as0 = *(const float4*)(attS + cg * 4);
    float4 as1 = make_float4(0.f, 0.f, 0.f, 0.f);
    if constexpr (NB == 2) as1 = *(const float4*)(attS + 64 + cg * 4);
#pragma unroll
    for (int j = 0; j < 4; ++j) {
        int gr = m0 + rg * 4 + j;
        bool ok = gr < M;
        if (ok) {
            *(float4*)(H + (size_t)gr * C + cg * 4) = acc[j][0];
            if constexpr (NB == 2)
                *(float4*)(H + (size_t)gr * C + 64 + cg * 4) = acc[j][1];
        }
        float ps = acc[j][0].x * as0.x + acc[j][0].y * as0.y +
                   acc[j][0].z * as0.z + acc[j][0].w * as0.w;
        if constexpr (NB == 2)
            ps += acc[j][1].x * as1.x + acc[j][1].y * as1.y +
                  acc[j][1].z * as1.z + acc[j][1].w * as1.w;
#pragma unroll
        for (int o = 8; o; o >>= 1) ps += __shfl_xor(ps, o, 64);
        if (cg == 0 && ok) { aS[gr] = ps; aD[gr] = pd[j]; }
    }
}

// Grouped accumulate of one <=64-edge chunk: 4 groups of 16 lanes, each group
// handles one edge per step with dwordx4 loads. Padded edges carry w=0.
template <int C>
__device__ __forceinline__ void agg_chunk(float w, int sj, int cnt, int lane,
                                          const float* __restrict__ hsrc, float* acc) {
    const int g = lane >> 4;
    const int l = lane & 15;
    const int jm = (cnt + 3) >> 2;
#pragma unroll 4
    for (int j = 0; j < jm; ++j) {
        int e = j * 4 + g;
        float wj = __shfl(w, e, 64);
        int sr = __shfl(sj, e, 64);
        if constexpr (C == 128) {
            const float4* p = (const float4*)(hsrc + ((size_t)sr << 7)) + l * 2;
            float4 v0 = p[0];
            float4 v1 = p[1];
            acc[0] += wj * v0.x; acc[1] += wj * v0.y; acc[2] += wj * v0.z; acc[3] += wj * v0.w;
            acc[4] += wj * v1.x; acc[5] += wj * v1.y; acc[6] += wj * v1.z; acc[7] += wj * v1.w;
        } else {
            const float4* p = (const float4*)(hsrc + ((size_t)sr << 6)) + l;
            float4 v = p[0];
            acc[0] += wj * v.x; acc[1] += wj * v.y; acc[2] += wj * v.z; acc[3] += wj * v.w;
        }
    }
}

// One wave per destination node: segment softmax + weighted aggregation.
template <int C, bool RELU>
__global__ __launch_bounds__(256) void aggregate_kernel(
    const int* __restrict__ offs, const int* __restrict__ srcs,
    const float* __restrict__ hsrc, const float* __restrict__ aS,
    const float* __restrict__ aD, const float* __restrict__ bias,
    float* __restrict__ out, int n) {
    int node = (int)((blockIdx.x * blockDim.x + threadIdx.x) >> 6);
    int lane = threadIdx.x & 63;
    if (node >= n) return;
    int beg = offs[node], end = offs[node + 1];
    int deg = end - beg;
    float ad = aD[node];

    constexpr int NA = (C == 128) ? 8 : 4;
    float acc[NA];
#pragma unroll
    for (int i = 0; i < NA; ++i) acc[i] = 0.f;

    if (deg <= 64) {
        // ---- fused fast path: one gather + one exp per edge ----
        int i = beg + lane;
        int sj = 0;
        float lv = -INFINITY;
        if (i < end) {
            sj = srcs[i];
            float l = aS[sj] + ad;
            lv = (l > 0.f) ? l : 0.2f * l;
        }
        float m = lv;
#pragma unroll
        for (int o = 32; o; o >>= 1) m = fmaxf(m, __shfl_xor(m, o, 64));
        float e = (i < end) ? __expf(lv - m) : 0.f;
        float s = e;
#pragma unroll
        for (int o = 32; o; o >>= 1) s += __shfl_xor(s, o, 64);
        float w = e * (1.f / (s + 1e-16f));
        agg_chunk<C>(w, sj, deg, lane, hsrc, acc);
    } else {
        // ---- generic chunked path (deg > 64, rare) ----
        float m = -INFINITY;
        for (int i = beg + lane; i < end; i += 64) {
            float l = aS[srcs[i]] + ad;
            l = (l > 0.f) ? l : 0.2f * l;
            m = fmaxf(m, l);
        }
#pragma unroll
        for (int o = 32; o; o >>= 1) m = fmaxf(m, __shfl_xor(m, o, 64));
        float s = 0.f;
        for (int i = beg + lane; i < end; i += 64) {
            float l = aS[srcs[i]] + ad;
            l = (l > 0.f) ? l : 0.2f * l;
            s += __expf(l - m);
        }
#pragma unroll
        for (int o = 32; o; o >>= 1) s += __shfl_xor(s, o, 64);
        float inv = 1.f / (s + 1e-16f);
        for (int base = beg; base < end; base += 64) {
            int i = base + lane;
            int sj = 0;
            float w = 0.f;
            if (i < end) {
                sj = srcs[i];
                float l = aS[sj] + ad;
                l = (l > 0.f) ? l : 0.2f * l;
                w = __expf(l - m) * inv;
            }
            agg_chunk<C>(w, sj, min(64, end - base), lane, hsrc, acc);
        }
    }

    // cross-group reduce: groups 0..3 hold partial sums for the same cols
#pragma unroll
    for (int i = 0; i < NA; ++i) {
        acc[i] += __shfl_xor(acc[i], 16, 64);
        acc[i] += __shfl_xor(acc[i], 32, 64);
    }

    if (lane < 16) {
        if constexpr (C == 128) {
            int c0 = lane * 8;
            const float4* b4 = (const float4*)(bias + c0);
            float4 b0 = b4[0], b1 = b4[1];
            float4 o0 = make_float4(acc[0] + b0.x, acc[1] + b0.y, acc[2] + b0.z, acc[3] + b0.w);
            float4 o1 = make_float4(acc[4] + b1.x, acc[5] + b1.y, acc[6] + b1.z, acc[7] + b1.w);
            if (RELU) {
                o0.x = fmaxf(o0.x, 0.f); o0.y = fmaxf(o0.y, 0.f);
                o0.z = fmaxf(o0.z, 0.f); o0.w = fmaxf(o0.w, 0.f);
                o1.x = fmaxf(o1.x, 0.f); o1.y = fmaxf(o1.y, 0.f);
                o1.z = fmaxf(o1.z, 0.f); o1.w = fmaxf(o1.w, 0.f);
            }
            float4* op = (float4*)(out + (size_t)node * 128 + c0);
            op[0] = o0;
            op[1] = o1;
        } else {
            int c0 = lane * 4;
            float4 b0 = *(const float4*)(bias + c0);
            float4 o0 = make_float4(acc[0] + b0.x, acc[1] + b0.y, acc[2] + b0.z, acc[3] + b0.w);
            if (RELU) {
                o0.x = fmaxf(o0.x, 0.f); o0.y = fmaxf(o0.y, 0.f);
                o0.z = fmaxf(o0.z, 0.f); o0.w = fmaxf(o0.w, 0.f);
            }
            *(float4*)(out + (size_t)node * 64 + c0) = o0;
        }
    }
}

extern "C" void kernel_launch(void* const* d_in, const int* in_sizes, int n_in,
                              void* d_out, int out_size, void* d_ws, size_t ws_size,
                              hipStream_t stream) {
    const float* x     = (const float*)d_in[0];
    const int*   edge  = (const int*)d_in[1];
    const float* W1s   = (const float*)d_in[2];
    const float* W1d   = (const float*)d_in[3];
    const float* att1s = (const float*)d_in[4];
    const float* att1d = (const float*)d_in[5];
    const float* b1    = (const float*)d_in[6];
    const float* W2s   = (const float*)d_in[7];
    const float* W2d   = (const float*)d_in[8];
    const float* att2s = (const float*)d_in[9];
    const float* att2d = (const float*)d_in[10];
    const float* b2    = (const float*)d_in[11];

    const int N = in_sizes[0] / 128;
    const int E = in_sizes[1] / 2;
    const int* srcI = edge;
    const int* dstI = edge + E;

    // workspace carve (256-B aligned)
    size_t off = 0;
    auto alloc = [&](size_t bytes) {
        void* p = (char*)d_ws + off;
        off += (bytes + 255) & ~(size_t)255;
        return p;
    };
    int*   offs  = (int*)alloc((size_t)(N + 1) * 4);
    int*   cur   = (int*)alloc((size_t)N * 4);
    int*   srcs  = (int*)alloc((size_t)E * 4);
    int*   bsums = (int*)alloc(512 * 4);
    float* watt1 = (float*)alloc(128 * 4);
    float* watt2 = (float*)alloc(128 * 4);
    float* a_s   = (float*)alloc((size_t)N * 4);
    float* a_d   = (float*)alloc((size_t)N * 4);
    float* h_s   = (float*)alloc((size_t)N * 128 * 4);  // h1_src then h2_src
    float* h1    = (float*)alloc((size_t)N * 128 * 4);  // relu(layer1 out)

    hipMemsetAsync(cur, 0, (size_t)N * 4, stream);
    matvec_kernel<<<1, 128, 0, stream>>>(W1d, att1d, watt1, 128, 128);
    matvec_kernel<<<1, 128, 0, stream>>>(W2d, att2d, watt2, 128, 64);

    int nb = (N + 255) / 256;
    hist_kernel<<<(E + 255) / 256, 256, 0, stream>>>(dstI, cur, E);
    scan_block_kernel<<<nb, 256, 0, stream>>>(cur, offs, bsums, N);
    scan_top_kernel<<<1, 512, 0, stream>>>(bsums, nb);
    scan_fin_kernel<<<nb, 256, 0, stream>>>(offs, bsums, cur, N, E);
    scatter_kernel<<<(E + 255) / 256, 256, 0, stream>>>(srcI, dstI, cur, srcs, E);

    int gblk = (N + 63) / 64;
    gemm_att_kernel<128><<<gblk, 256, 0, stream>>>(x, W1s, att1s, watt1, h_s, a_s, a_d, N);
    aggregate_kernel<128, true><<<(N + 3) / 4, 256, 0, stream>>>(offs, srcs, h_s, a_s, a_d, b1, h1, N);
    gemm_att_kernel<64><<<gblk, 256, 0, stream>>>(h1, W2s, att2s, watt2, h_s, a_s, a_d, N);
    aggregate_kernel<64, false><<<(N + 3) / 4, 256, 0, stream>>>(offs, srcs, h_s, a_s, a_d, b2, (float*)d_out, N);
}

// Round 4
// 462.016 us; speedup vs baseline: 1.5907x; 1.2905x over previous
//
#include <hip/hip_runtime.h>

// ---------------------------------------------------------------------------
// GAT 2-layer encoder. N=100k nodes, E=1.6M edges, 128->128(relu)->64.
//   a_dst = x . (W_dst @ att_dst)  (h_dst never materialized)
//   CSR-by-dst via two-level counting sort (256 coarse buckets of 512 nodes,
//   then per-bucket 512-bin LDS sort) -- avoids the 16x write amplification
//   of a single-pass random atomic scatter.
//   register-tiled fp32 GEMM (4x8 per thread, conflict-free LDS)
//   one wave per dst node: fused segment softmax + grouped gather-aggregate
// ---------------------------------------------------------------------------

typedef unsigned long long u64;

__global__ void matvec_kernel(const float* __restrict__ W, const float* __restrict__ a,
                              float* __restrict__ out, int rows, int cols) {
    int i = blockIdx.x * blockDim.x + threadIdx.x;
    if (i >= rows) return;
    float s = 0.f;
    for (int j = 0; j < cols; ++j) s += W[i * cols + j] * a[j];
    out[i] = s;
}

// ---- CSR build: two-level counting sort ----
// K1: coarse histogram over 256 buckets (dst>>9)
__global__ __launch_bounds__(256) void bhist_kernel(const int* __restrict__ dst,
                                                    int* __restrict__ gh, int E) {
    __shared__ int h[256];
    h[threadIdx.x] = 0;
    __syncthreads();
    int base = blockIdx.x * 4096;
    int lim = min(base + 4096, E);
    for (int i = base + threadIdx.x; i < lim; i += 256)
        atomicAdd(&h[dst[i] >> 9], 1);
    __syncthreads();
    int v = h[threadIdx.x];
    if (v) atomicAdd(&gh[threadIdx.x], v);
}

// K2: exclusive scan of the 256 bucket counts; also seeds cursors and offs[N]
__global__ __launch_bounds__(256) void bscan_kernel(const int* __restrict__ gh,
                                                    int* __restrict__ bbase,
                                                    int* __restrict__ gcur,
                                                    int* __restrict__ offs, int N, int E) {
    __shared__ int s[256];
    int t = threadIdx.x;
    int v = gh[t];
    s[t] = v;
    __syncthreads();
    for (int o = 1; o < 256; o <<= 1) {
        int u = (t >= o) ? s[t - o] : 0;
        __syncthreads();
        s[t] += u;
        __syncthreads();
    }
    int excl = s[t] - v;
    bbase[t] = excl;
    gcur[t] = excl;
    if (t == 255) { bbase[256] = E; offs[N] = E; }
}

// K3: coarse ranked scatter of packed (dst,src) pairs into bucket regions
__global__ __launch_bounds__(256) void bscatter_kernel(const int* __restrict__ src,
                                                       const int* __restrict__ dst,
                                                       int* __restrict__ gcur,
                                                       u64* __restrict__ pairs, int E) {
    __shared__ int h[256];
    __shared__ int rbase[256];
    const int tid = threadIdx.x;
    h[tid] = 0;
    __syncthreads();
    const int base = blockIdx.x * 4096;
    u64 pv[16];
    int rk[16];
    int bk[16];
#pragma unroll 16
    for (int k = 0; k < 16; ++k) {
        int i = base + k * 256 + tid;
        if (i < E) {
            int d = dst[i];
            int b = d >> 9;
            bk[k] = b;
            pv[k] = ((u64)(unsigned)d << 32) | (unsigned)src[i];
            rk[k] = atomicAdd(&h[b], 1);
        } else {
            bk[k] = -1;
        }
    }
    __syncthreads();
    int c = h[tid];
    rbase[tid] = c ? atomicAdd(&gcur[tid], c) : 0;
    __syncthreads();
#pragma unroll 16
    for (int k = 0; k < 16; ++k)
        if (bk[k] >= 0) pairs[(size_t)rbase[bk[k]] + rk[k]] = pv[k];
}

// K4: per-bucket fine counting sort (512 bins); writes offs + srcs
__global__ __launch_bounds__(512) void bsort_kernel(const u64* __restrict__ pairs,
                                                    const int* __restrict__ bbase,
                                                    int* __restrict__ offs,
                                                    int* __restrict__ srcs, int N) {
    __shared__ int h[512];
    __shared__ int cur[512];
    const int t = threadIdx.x;
    const int b = blockIdx.x;
    const int beg = bbase[b], end = bbase[b + 1];
    h[t] = 0;
    __syncthreads();
    for (int i = beg + t; i < end; i += 512)
        atomicAdd(&h[(int)(pairs[i] >> 32) & 511], 1);
    __syncthreads();
    int v = h[t];
    cur[t] = v;
    __syncthreads();
    for (int o = 1; o < 512; o <<= 1) {
        int u = (t >= o) ? cur[t - o] : 0;
        __syncthreads();
        cur[t] += u;
        __syncthreads();
    }
    int pos0 = beg + cur[t] - v;
    __syncthreads();
    cur[t] = pos0;
    int g = (b << 9) + t;
    if (g < N) offs[g] = pos0;
    __syncthreads();
    for (int i = beg + t; i < end; i += 512) {
        u64 p = pairs[i];
        int local = (int)(p >> 32) & 511;
        int pp = atomicAdd(&cur[local], 1);
        srcs[pp] = (int)(p & 0xffffffffu);
    }
}

// H = X @ W  (X:[M,128], W:[128,C]); fused epilogue:
//   aS[m] = H[m,:] . attS     aD[m] = X[m,:] . wda
template <int C>
__global__ __launch_bounds__(256) void gemm_att_kernel(
    const float* __restrict__ X, const float* __restrict__ W,
    const float* __restrict__ attS, const float* __restrict__ wda,
    float* __restrict__ H, float* __restrict__ aS, float* __restrict__ aD, int M) {
    constexpr int NB = (C == 128) ? 2 : 1;
    __shared__ float4 Xs[16 * 65];          // [k4][row], coeff 65 rotates banks
    __shared__ float  Ws[64 * C];           // k-major half of W

    const int t  = threadIdx.x;
    const int m0 = blockIdx.x * 64;
    const int rg = t >> 4;                  // 0..15 row group
    const int cg = t & 15;                  // 0..15 col group

    float4 acc[4][NB];
#pragma unroll
    for (int j = 0; j < 4; ++j)
#pragma unroll
        for (int b = 0; b < NB; ++b) acc[j][b] = make_float4(0.f, 0.f, 0.f, 0.f);
    float pd[4] = {0.f, 0.f, 0.f, 0.f};

    for (int kk = 0; kk < 128; kk += 64) {
        {
            const float4* Wg = (const float4*)(W + (size_t)kk * C);
            float4* WsV = (float4*)Ws;
#pragma unroll
            for (int i = 0; i < C / 16; ++i) WsV[i * 256 + t] = Wg[i * 256 + t];
        }
#pragma unroll
        for (int i = 0; i < 4; ++i) {
            int f4 = i * 256 + t;
            int row = f4 >> 4;
            int k4 = f4 & 15;
            int gr = m0 + row;
            float4 v = make_float4(0.f, 0.f, 0.f, 0.f);
            if (gr < M) v = *(const float4*)(X + (size_t)gr * 128 + kk + k4 * 4);
            Xs[k4 * 65 + row] = v;
        }
        __syncthreads();

#pragma unroll 4
        for (int k4 = 0; k4 < 16; ++k4) {
            float4 a[4];
#pragma unroll
            for (int j = 0; j < 4; ++j) a[j] = Xs[k4 * 65 + rg * 4 + j];
            const float* wrow = Ws + k4 * 4 * C;
            const float* wd = wda + kk + k4 * 4;
#pragma unroll
            for (int u = 0; u < 4; ++u) {
                float4 b0 = *(const float4*)(wrow + u * C + cg * 4);
                float wdu = wd[u];
                float av[4];
#pragma unroll
                for (int j = 0; j < 4; ++j) av[j] = ((const float*)&a[j])[u];
#pragma unroll
                for (int j = 0; j < 4; ++j) {
                    acc[j][0].x += av[j] * b0.x;
                    acc[j][0].y += av[j] * b0.y;
                    acc[j][0].z += av[j] * b0.z;
                    acc[j][0].w += av[j] * b0.w;
                    pd[j] += av[j] * wdu;
                }
                if constexpr (NB == 2) {
                    float4 b1 = *(const float4*)(wrow + u * C + 64 + cg * 4);
#pragma unroll
                    for (int j = 0; j < 4; ++j) {
                        acc[j][1].x += av[j] * b1.x;
                        acc[j][1].y += av[j] * b1.y;
                        acc[j][1].z += av[j] * b1.z;
                        acc[j][1].w += av[j] * b1.w;
                    }
                }
            }
        }
        __syncthreads();
    }

    float4 as0 = *(const float4*)(attS + cg * 4);
    float4 as1 = make_float4(0.f, 0.f, 0.f, 0.f);
    if constexpr (NB == 2) as1 = *(const float4*)(attS + 64 + cg * 4);
#pragma unroll
    for (int j = 0; j < 4; ++j) {
        int gr = m0 + rg * 4 + j;
        bool ok = gr < M;
        if (ok) {
            *(float4*)(H + (size_t)gr * C + cg * 4) = acc[j][0];
            if constexpr (NB == 2)
                *(float4*)(H + (size_t)gr * C + 64 + cg * 4) = acc[j][1];
        }
        float ps = acc[j][0].x * as0.x + acc[j][0].y * as0.y +
                   acc[j][0].z * as0.z + acc[j][0].w * as0.w;
        if constexpr (NB == 2)
            ps += acc[j][1].x * as1.x + acc[j][1].y * as1.y +
                  acc[j][1].z * as1.z + acc[j][1].w * as1.w;
#pragma unroll
        for (int o = 8; o; o >>= 1) ps += __shfl_xor(ps, o, 64);
        if (cg == 0 && ok) { aS[gr] = ps; aD[gr] = pd[j]; }
    }
}

// Grouped accumulate of one <=64-edge chunk: 4 groups of 16 lanes, each group
// handles one edge per step with dwordx4 loads. Padded edges carry w=0.
template <int C>
__device__ __forceinline__ void agg_chunk(float w, int sj, int cnt, int lane,
                                          const float* __restrict__ hsrc, float* acc) {
    const int g = lane >> 4;
    const int l = lane & 15;
    const int jm = (cnt + 3) >> 2;
#pragma unroll 4
    for (int j = 0; j < jm; ++j) {
        int e = j * 4 + g;
        float wj = __shfl(w, e, 64);
        int sr = __shfl(sj, e, 64);
        if constexpr (C == 128) {
            const float4* p = (const float4*)(hsrc + ((size_t)sr << 7)) + l * 2;
            float4 v0 = p[0];
            float4 v1 = p[1];
            acc[0] += wj * v0.x; acc[1] += wj * v0.y; acc[2] += wj * v0.z; acc[3] += wj * v0.w;
            acc[4] += wj * v1.x; acc[5] += wj * v1.y; acc[6] += wj * v1.z; acc[7] += wj * v1.w;
        } else {
            const float4* p = (const float4*)(hsrc + ((size_t)sr << 6)) + l;
            float4 v = p[0];
            acc[0] += wj * v.x; acc[1] += wj * v.y; acc[2] += wj * v.z; acc[3] += wj * v.w;
        }
    }
}

// One wave per destination node: segment softmax + weighted aggregation.
template <int C, bool RELU>
__global__ __launch_bounds__(256) void aggregate_kernel(
    const int* __restrict__ offs, const int* __restrict__ srcs,
    const float* __restrict__ hsrc, const float* __restrict__ aS,
    const float* __restrict__ aD, const float* __restrict__ bias,
    float* __restrict__ out, int n) {
    int node = (int)((blockIdx.x * blockDim.x + threadIdx.x) >> 6);
    int lane = threadIdx.x & 63;
    if (node >= n) return;
    int beg = offs[node], end = offs[node + 1];
    int deg = end - beg;
    float ad = aD[node];

    constexpr int NA = (C == 128) ? 8 : 4;
    float acc[NA];
#pragma unroll
    for (int i = 0; i < NA; ++i) acc[i] = 0.f;

    if (deg <= 64) {
        int i = beg + lane;
        int sj = 0;
        float lv = -INFINITY;
        if (i < end) {
            sj = srcs[i];
            float l = aS[sj] + ad;
            lv = (l > 0.f) ? l : 0.2f * l;
        }
        float m = lv;
#pragma unroll
        for (int o = 32; o; o >>= 1) m = fmaxf(m, __shfl_xor(m, o, 64));
        float e = (i < end) ? __expf(lv - m) : 0.f;
        float s = e;
#pragma unroll
        for (int o = 32; o; o >>= 1) s += __shfl_xor(s, o, 64);
        float w = e * (1.f / (s + 1e-16f));
        agg_chunk<C>(w, sj, deg, lane, hsrc, acc);
    } else {
        float m = -INFINITY;
        for (int i = beg + lane; i < end; i += 64) {
            float l = aS[srcs[i]] + ad;
            l = (l > 0.f) ? l : 0.2f * l;
            m = fmaxf(m, l);
        }
#pragma unroll
        for (int o = 32; o; o >>= 1) m = fmaxf(m, __shfl_xor(m, o, 64));
        float s = 0.f;
        for (int i = beg + lane; i < end; i += 64) {
            float l = aS[srcs[i]] + ad;
            l = (l > 0.f) ? l : 0.2f * l;
            s += __expf(l - m);
        }
#pragma unroll
        for (int o = 32; o; o >>= 1) s += __shfl_xor(s, o, 64);
        float inv = 1.f / (s + 1e-16f);
        for (int base = beg; base < end; base += 64) {
            int i = base + lane;
            int sj = 0;
            float w = 0.f;
            if (i < end) {
                sj = srcs[i];
                float l = aS[sj] + ad;
                l = (l > 0.f) ? l : 0.2f * l;
                w = __expf(l - m) * inv;
            }
            agg_chunk<C>(w, sj, min(64, end - base), lane, hsrc, acc);
        }
    }

#pragma unroll
    for (int i = 0; i < NA; ++i) {
        acc[i] += __shfl_xor(acc[i], 16, 64);
        acc[i] += __shfl_xor(acc[i], 32, 64);
    }

    if (lane < 16) {
        if constexpr (C == 128) {
            int c0 = lane * 8;
            const float4* b4 = (const float4*)(bias + c0);
            float4 b0 = b4[0], b1 = b4[1];
            float4 o0 = make_float4(acc[0] + b0.x, acc[1] + b0.y, acc[2] + b0.z, acc[3] + b0.w);
            float4 o1 = make_float4(acc[4] + b1.x, acc[5] + b1.y, acc[6] + b1.z, acc[7] + b1.w);
            if (RELU) {
                o0.x = fmaxf(o0.x, 0.f); o0.y = fmaxf(o0.y, 0.f);
                o0.z = fmaxf(o0.z, 0.f); o0.w = fmaxf(o0.w, 0.f);
                o1.x = fmaxf(o1.x, 0.f); o1.y = fmaxf(o1.y, 0.f);
                o1.z = fmaxf(o1.z, 0.f); o1.w = fmaxf(o1.w, 0.f);
            }
            float4* op = (float4*)(out + (size_t)node * 128 + c0);
            op[0] = o0;
            op[1] = o1;
        } else {
            int c0 = lane * 4;
            float4 b0 = *(const float4*)(bias + c0);
            float4 o0 = make_float4(acc[0] + b0.x, acc[1] + b0.y, acc[2] + b0.z, acc[3] + b0.w);
            if (RELU) {
                o0.x = fmaxf(o0.x, 0.f); o0.y = fmaxf(o0.y, 0.f);
                o0.z = fmaxf(o0.z, 0.f); o0.w = fmaxf(o0.w, 0.f);
            }
            *(float4*)(out + (size_t)node * 64 + c0) = o0;
        }
    }
}

extern "C" void kernel_launch(void* const* d_in, const int* in_sizes, int n_in,
                              void* d_out, int out_size, void* d_ws, size_t ws_size,
                              hipStream_t stream) {
    const float* x     = (const float*)d_in[0];
    const int*   edge  = (const int*)d_in[1];
    const float* W1s   = (const float*)d_in[2];
    const float* W1d   = (const float*)d_in[3];
    const float* att1s = (const float*)d_in[4];
    const float* att1d = (const float*)d_in[5];
    const float* b1    = (const float*)d_in[6];
    const float* W2s   = (const float*)d_in[7];
    const float* W2d   = (const float*)d_in[8];
    const float* att2s = (const float*)d_in[9];
    const float* att2d = (const float*)d_in[10];
    const float* b2    = (const float*)d_in[11];

    const int N = in_sizes[0] / 128;
    const int E = in_sizes[1] / 2;
    const int* srcI = edge;
    const int* dstI = edge + E;

    // workspace carve (256-B aligned)
    size_t off = 0;
    auto alloc = [&](size_t bytes) {
        void* p = (char*)d_ws + off;
        off += (bytes + 255) & ~(size_t)255;
        return p;
    };
    int*   offs  = (int*)alloc((size_t)(N + 1) * 4);
    int*   srcs  = (int*)alloc((size_t)E * 4);
    int*   gh    = (int*)alloc(256 * 4);
    int*   bbase = (int*)alloc(257 * 4);
    int*   gcur  = (int*)alloc(256 * 4);
    float* watt1 = (float*)alloc(128 * 4);
    float* watt2 = (float*)alloc(128 * 4);
    float* a_s   = (float*)alloc((size_t)N * 4);
    float* a_d   = (float*)alloc((size_t)N * 4);
    float* h_s   = (float*)alloc((size_t)N * 128 * 4);  // h1_src then h2_src
    float* h1    = (float*)alloc((size_t)N * 128 * 4);  // relu(layer1 out)
    // pairs is dead before gemm1 writes h_s (in-order stream) -> alias
    u64*   pairs = (u64*)h_s;

    hipMemsetAsync(gh, 0, 256 * 4, stream);
    matvec_kernel<<<1, 128, 0, stream>>>(W1d, att1d, watt1, 128, 128);
    matvec_kernel<<<1, 128, 0, stream>>>(W2d, att2d, watt2, 128, 64);

    const int nbE = (E + 4095) / 4096;
    const int nbuckets = (N + 511) >> 9;
    bhist_kernel<<<nbE, 256, 0, stream>>>(dstI, gh, E);
    bscan_kernel<<<1, 256, 0, stream>>>(gh, bbase, gcur, offs, N, E);
    bscatter_kernel<<<nbE, 256, 0, stream>>>(srcI, dstI, gcur, pairs, E);
    bsort_kernel<<<nbuckets, 512, 0, stream>>>(pairs, bbase, offs, srcs, N);

    int gblk = (N + 63) / 64;
    gemm_att_kernel<128><<<gblk, 256, 0, stream>>>(x, W1s, att1s, watt1, h_s, a_s, a_d, N);
    aggregate_kernel<128, true><<<(N + 3) / 4, 256, 0, stream>>>(offs, srcs, h_s, a_s, a_d, b1, h1, N);
    gemm_att_kernel<64><<<gblk, 256, 0, stream>>>(h1, W2s, att2s, watt2, h_s, a_s, a_d, N);
    aggregate_kernel<64, false><<<(N + 3) / 4, 256, 0, stream>>>(offs, srcs, h_s, a_s, a_d, b2, (float*)d_out, N);
}